// Round 15
// baseline (388.395 us; speedup 1.0000x reference)
//
#include <hip/hip_runtime.h>
#include <hip/hip_bf16.h>
#include <math.h>

#define FIN 35
#define FOUT 128
#define NGRAPHS 512
#define PWA 32          // pass-A panel width (fp16) = 64 B rows, feats 0..31
#define PWB 4           // pass-B panel width (fp16) = 8 B rows, feats 32..34 + pad
#define PW2 16          // s-output panel width (f32), layout [3][N][16] as before
#define RP 36           // padded LDS row (floats), 144 B: float4-aligned
#define STRIP1 64       // nodes per block in nu1 (4 waves x 16 nodes)
#define STRIP2 32       // nodes per block in nu2
#define CHUNK 8192      // edges per block in hist1/scatter1
#define MAXBUCK 512     // >= ceil(N/256)
#define MAXBE 12288     // csr2 LDS edge-staging capacity (48 KB)

typedef _Float16 half8 __attribute__((ext_vector_type(8)));
typedef _Float16 half4 __attribute__((ext_vector_type(4)));

// ---------- helpers ----------
__device__ __forceinline__ unsigned int enc_f32(float f) {
    unsigned int u = __float_as_uint(f);
    return (u & 0x80000000u) ? ~u : (u | 0x80000000u);
}
__device__ __forceinline__ float dec_f32(unsigned int u) {
    unsigned int b = (u & 0x80000000u) ? (u ^ 0x80000000u) : ~u;
    return __uint_as_float(b);
}

// ---------- CSR build via two-level LDS radix partition (no global atomics) ----------

__global__ __launch_bounds__(256) void hist1_kernel(const int* __restrict__ dst,
                                                    int* __restrict__ counts,
                                                    int E, int nblk1, int nbuck) {
    __shared__ int h[MAXBUCK];
    for (int t = threadIdx.x; t < nbuck; t += 256) h[t] = 0;
    __syncthreads();
    int base = blockIdx.x * CHUNK;
    int end = min(base + CHUNK, E);
    for (int e = base + threadIdx.x; e < end; e += 256)
        atomicAdd(&h[dst[e] >> 8], 1);
    __syncthreads();
    for (int t = threadIdx.x; t < nbuck; t += 256)
        counts[t * nblk1 + blockIdx.x] = h[t];
}

__global__ void partial_reduce_kernel(const int* __restrict__ v_in, int* __restrict__ partial, int SC) {
    int i = blockIdx.x * 256 + threadIdx.x;
    int v = (i < SC) ? v_in[i] : 0;
    #pragma unroll
    for (int off = 32; off > 0; off >>= 1) v += __shfl_down(v, off, 64);
    __shared__ int w[4];
    if ((threadIdx.x & 63) == 0) w[threadIdx.x >> 6] = v;
    __syncthreads();
    if (threadIdx.x == 0) partial[blockIdx.x] = w[0] + w[1] + w[2] + w[3];
}

__global__ void scan_partials_kernel(int* __restrict__ partial, int NB) {
    __shared__ int lds[1024];
    int t = threadIdx.x;
    int v = (t < NB) ? partial[t] : 0;
    lds[t] = v;
    __syncthreads();
    for (int off = 1; off < 1024; off <<= 1) {
        int tv = (t >= off) ? lds[t - off] : 0;
        __syncthreads();
        lds[t] += tv;
        __syncthreads();
    }
    if (t < NB) partial[t] = lds[t] - v;   // exclusive
}

__global__ void scan_final_kernel(const int* __restrict__ v_in, const int* __restrict__ partial,
                                  int* __restrict__ outx, int SC) {
    __shared__ int lds[256];
    int i = blockIdx.x * 256 + threadIdx.x;
    int v = (i < SC) ? v_in[i] : 0;
    lds[threadIdx.x] = v;
    __syncthreads();
    for (int off = 1; off < 256; off <<= 1) {
        int tv = (threadIdx.x >= off) ? lds[threadIdx.x - off] : 0;
        __syncthreads();
        lds[threadIdx.x] += tv;
        __syncthreads();
    }
    int excl = lds[threadIdx.x] - v + partial[blockIdx.x];
    if (i < SC) {
        outx[i] = excl;
        if (i == SC - 1) outx[SC] = excl + v;
    }
}

__global__ __launch_bounds__(256) void scatter1_kernel(const int* __restrict__ src,
                                                       const int* __restrict__ dst,
                                                       const int* __restrict__ offs,
                                                       int* __restrict__ ebuf,
                                                       int E, int nblk1, int nbuck) {
    __shared__ int cur[MAXBUCK];
    for (int t = threadIdx.x; t < nbuck; t += 256) cur[t] = offs[t * nblk1 + blockIdx.x];
    __syncthreads();
    int base = blockIdx.x * CHUNK;
    int end = min(base + CHUNK, E);
    for (int e = base + threadIdx.x; e < end; e += 256) {
        int d = dst[e];
        int p = atomicAdd(&cur[d >> 8], 1);
        ebuf[p] = (src[e] << 8) | (d & 255);
    }
}

// Level-2: one block per bucket; bucket edges staged in LDS (skips the ebuf re-read).
__global__ __launch_bounds__(256) void csr2_kernel(const int* __restrict__ ebuf,
                                                   const int* __restrict__ offs,
                                                   int* __restrict__ row_ptr,
                                                   int* __restrict__ esrc,
                                                   int E, int nblk1, int nbuck, int N) {
    __shared__ int h[256];
    __shared__ int scn[256];
    __shared__ int e_sh[MAXBE];
    int b = blockIdx.x;
    int t = threadIdx.x;
    int bstart = offs[b * nblk1];
    int bend = (b + 1 < nbuck) ? offs[(b + 1) * nblk1] : E;
    int cnt = bend - bstart;
    bool fit = (cnt <= MAXBE);

    if (fit)
        for (int k = t; k < cnt; k += 256) e_sh[k] = ebuf[bstart + k];
    h[t] = 0;
    __syncthreads();
    for (int k = t; k < cnt; k += 256)
        atomicAdd(&h[(fit ? e_sh[k] : ebuf[bstart + k]) & 255], 1);
    __syncthreads();

    int v = h[t];
    scn[t] = v;
    __syncthreads();
    for (int off = 1; off < 256; off <<= 1) {
        int tv = (t >= off) ? scn[t - off] : 0;
        __syncthreads();
        scn[t] += tv;
        __syncthreads();
    }
    int excl = scn[t] - v;
    int node = (b << 8) + t;
    if (node < N) row_ptr[node] = bstart + excl;
    if (b == 0 && t == 0) row_ptr[N] = E;

    __syncthreads();
    h[t] = bstart + excl;
    __syncthreads();
    for (int k = t; k < cnt; k += 256) {
        int e = fit ? e_sh[k] : ebuf[bstart + k];
        int p = atomicAdd(&h[e & 255], 1);
        esrc[p] = e >> 8;
    }
}

// ---------- repack x[N][35] -> xA[N][32] (64 B rows) + xB[N][4] (8 B rows, pad zero) ----------
__global__ void repack_kernel(const float* __restrict__ x,
                              _Float16* __restrict__ xA, _Float16* __restrict__ xB, int N) {
    int t = blockIdx.x * 256 + threadIdx.x;          // < N*36
    int NA = N * PWA;
    if (t < NA) {
        int n = t >> 5;
        int f = t & 31;
        xA[t] = (_Float16)x[(long long)n * FIN + f];
    } else if (t < NA + N * PWB) {
        int c = t - NA;
        int n = c >> 2;
        int f3 = c & 3;
        float v = (f3 < 3) ? x[(long long)n * FIN + 32 + f3] : 0.0f;
        xB[c] = (_Float16)v;
    }
}

// ---------- two-pass XCD-affinity gather: 64 B rows (feats 0-31) + 8 B rows (32-34) ----------
// 2 random line transactions per edge (vs 3): pass A's four quad-lane 16 B loads hit one
// 64 B line within one wave instruction -> hardware-coalesced to a single transaction.
// Item = 8/node/pass, Wtot = 16N; flat share split means shares 0-3 serve pass A and
// 4-7 pass B: each XCD touches exactly ONE panel for its whole share (panel A 6.4 MB
// overflows 4 MB L2 ~40%, absorbed by L3; panel B 0.8 MB fully resident).
// 8N and WS are 256-multiples -> pass is wave-uniform; shfl groups never straddle cuts.
__global__ __launch_bounds__(256) void gather2_kernel(const _Float16* __restrict__ pA,
                                                      const _Float16* __restrict__ pB,
                                                      const int* __restrict__ row_ptr,
                                                      const int* __restrict__ esrc,
                                                      float* __restrict__ sp,
                                                      int N, int Wtot, int WS) {
    int q = blockIdx.x & 7;
    int m = blockIdx.x >> 3;
    int w = q * WS + m * 256 + threadIdx.x;
    int wend = min((q + 1) * WS, Wtot);
    if (w >= wend) return;
    int NI = N * 8;
    int pass = w / NI;                       // 0 = A (feats 0-31), 1 = B (feats 32-34)
    int t = w - pass * NI;
    int n = t >> 3;
    int b = row_ptr[n];
    int e = row_ptr[n + 1];
    int deg = e - b;

    if (pass == 0) {
        int quad = (t >> 1) & 3;             // feature octet within the 64 B row
        int q2 = t & 1;                      // edge-list half
        const _Float16* base = pA + (quad << 3);
        int k0 = b + ((deg * q2) >> 1);
        int k1 = b + ((deg * (q2 + 1)) >> 1);

        float a0[8] = {0,0,0,0,0,0,0,0}, a1[8] = {0,0,0,0,0,0,0,0};
        float a2[8] = {0,0,0,0,0,0,0,0}, a3[8] = {0,0,0,0,0,0,0,0};
        int k = k0;
        for (; k + 4 <= k1; k += 4) {
            int s0 = esrc[k], s1 = esrc[k + 1], s2 = esrc[k + 2], s3 = esrc[k + 3];
            half8 v0 = *(const half8*)(base + ((long long)s0 << 5));
            half8 v1 = *(const half8*)(base + ((long long)s1 << 5));
            half8 v2 = *(const half8*)(base + ((long long)s2 << 5));
            half8 v3 = *(const half8*)(base + ((long long)s3 << 5));
            #pragma unroll
            for (int i = 0; i < 8; ++i) {
                a0[i] += (float)v0[i];
                a1[i] += (float)v1[i];
                a2[i] += (float)v2[i];
                a3[i] += (float)v3[i];
            }
        }
        for (; k < k1; ++k) {
            half8 v = *(const half8*)(base + ((long long)esrc[k] << 5));
            #pragma unroll
            for (int i = 0; i < 8; ++i) a0[i] += (float)v[i];
        }

        float s[8];
        #pragma unroll
        for (int i = 0; i < 8; ++i) {
            float p = (a0[i] + a1[i]) + (a2[i] + a3[i]);
            p += __shfl_xor(p, 1, 64);       // combine the two q2 halves
            s[i] = p;
        }
        if (q2 == 0) {
            float inv = 1.0f / (float)max(deg, 1);
            // global feat base = 8*quad -> panel quad>>1, col (quad&1)*8
            float* outp = sp + ((long long)(quad >> 1) * N + n) * PW2 + ((quad & 1) << 3);
            float4 r0, r1;
            r0.x = s[0] * inv; r0.y = s[1] * inv; r0.z = s[2] * inv; r0.w = s[3] * inv;
            r1.x = s[4] * inv; r1.y = s[5] * inv; r1.z = s[6] * inv; r1.w = s[7] * inv;
            *(float4*)outp = r0;
            *(float4*)(outp + 4) = r1;
        }
    } else {
        int q8 = t & 7;                      // edge-list eighth
        int k0 = b + ((deg * q8) >> 3);
        int k1 = b + ((deg * (q8 + 1)) >> 3);

        float a0[4] = {0,0,0,0}, a1[4] = {0,0,0,0};
        int k = k0;
        for (; k + 2 <= k1; k += 2) {
            int s0 = esrc[k], s1 = esrc[k + 1];
            half4 v0 = *(const half4*)(pB + ((long long)s0 << 2));
            half4 v1 = *(const half4*)(pB + ((long long)s1 << 2));
            #pragma unroll
            for (int i = 0; i < 4; ++i) {
                a0[i] += (float)v0[i];
                a1[i] += (float)v1[i];
            }
        }
        for (; k < k1; ++k) {
            half4 v = *(const half4*)(pB + ((long long)esrc[k] << 2));
            #pragma unroll
            for (int i = 0; i < 4; ++i) a0[i] += (float)v[i];
        }

        float s[4];
        #pragma unroll
        for (int i = 0; i < 4; ++i) {
            float p = a0[i] + a1[i];
            p += __shfl_xor(p, 1, 64);
            p += __shfl_xor(p, 2, 64);
            p += __shfl_xor(p, 4, 64);
            s[i] = p;
        }
        if (q8 == 0) {
            float inv = 1.0f / (float)max(deg, 1);
            float4 r;
            r.x = s[0] * inv; r.y = s[1] * inv; r.z = s[2] * inv; r.w = s[3] * inv;
            *(float4*)(sp + ((long long)2 * N + n) * PW2) = r;   // panel 2, cols 0-3
        }
    }
}

// ---------- nu1: h1 = relu(agg@Wl1 + bl1 + x@Wr1) ----------
// Weights in registers (lane j holds column j), 4 waves x 16 nodes per block,
// float4 broadcast reads from padded (RP=36) LDS rows. Writes h1 in A/B panel layout.
__global__ __launch_bounds__(256) void nu1_kernel(const float* __restrict__ x,
                                                  const float* __restrict__ s1p,
                                                  const float* __restrict__ Wl,
                                                  const float* __restrict__ bl,
                                                  const float* __restrict__ Wr,
                                                  _Float16* __restrict__ h1A,
                                                  _Float16* __restrict__ h1B,
                                                  int N) {
    __shared__ float x_sh[STRIP1 * RP];
    __shared__ float s_sh[STRIP1 * RP];

    int node0 = blockIdx.x * STRIP1;
    if (node0 >= N) return;
    int nn = min(STRIP1, N - node0);
    int tot = nn * FIN;

    for (int t = threadIdx.x; t < STRIP1; t += 256) {
        x_sh[t * RP + 35] = 0.0f;
        s_sh[t * RP + 35] = 0.0f;
    }
    for (int t = threadIdx.x; t < tot; t += 256) {
        int nl = t / FIN;
        int i = t - nl * FIN;
        x_sh[nl * RP + i] = x[(long long)node0 * FIN + t];
        s_sh[nl * RP + i] = s1p[((long long)(i >> 4) * N + node0 + nl) * PW2 + (i & 15)];
    }
    __syncthreads();

    int wave = threadIdx.x >> 6;
    int j = threadIdx.x & 63;
    if (j >= FIN) return;                    // no further barriers below

    float wl[36], wr[36];
    #pragma unroll
    for (int i = 0; i < FIN; ++i) {
        wl[i] = Wl[i * FIN + j];
        wr[i] = Wr[i * FIN + j];
    }
    wl[35] = 0.0f; wr[35] = 0.0f;
    float blj = bl[j];

    int nstart = wave * 16;
    int nend = min(nstart + 16, nn);
    for (int nl = nstart; nl < nend; ++nl) {
        float acc = blj;
        #pragma unroll
        for (int c = 0; c < 9; ++c) {
            float4 sv = *(const float4*)&s_sh[nl * RP + 4 * c];
            float4 xv = *(const float4*)&x_sh[nl * RP + 4 * c];
            acc = fmaf(sv.x, wl[4 * c],     acc);
            acc = fmaf(sv.y, wl[4 * c + 1], acc);
            acc = fmaf(sv.z, wl[4 * c + 2], acc);
            acc = fmaf(sv.w, wl[4 * c + 3], acc);
            acc = fmaf(xv.x, wr[4 * c],     acc);
            acc = fmaf(xv.y, wr[4 * c + 1], acc);
            acc = fmaf(xv.z, wr[4 * c + 2], acc);
            acc = fmaf(xv.w, wr[4 * c + 3], acc);
        }
        acc = fmaxf(acc, 0.0f);
        long long node = node0 + nl;
        if (j < 32) {
            h1A[(node << 5) + j] = (_Float16)acc;
        } else {
            h1B[(node << 2) + (j - 32)] = (_Float16)acc;
            if (j == 34) h1B[(node << 2) + 3] = (_Float16)0.0f;   // keep pad clean
        }
    }
}

// ---------- nu2 + pool: h2 = agg@Wl2 + bl2 + h1@Wr2, segment-batched graph max ----------
__global__ __launch_bounds__(128) void nu2_pool_kernel(const _Float16* __restrict__ h1A,
                                                       const _Float16* __restrict__ h1B,
                                                       const float* __restrict__ s2p,
                                                       const float* __restrict__ Wl,
                                                       const float* __restrict__ bl,
                                                       const float* __restrict__ Wr,
                                                       const int* __restrict__ batch,
                                                       unsigned int* __restrict__ genc,
                                                       int N) {
    __shared__ float s_sh[STRIP2 * RP];
    __shared__ float h_sh[STRIP2 * RP];
    __shared__ int b_sh[STRIP2];
    int node0 = blockIdx.x * STRIP2;
    if (node0 >= N) return;
    int nn = min(STRIP2, N - node0);
    int tot = nn * FIN;

    for (int t = threadIdx.x; t < STRIP2; t += 128) {
        s_sh[t * RP + 35] = 0.0f;
        h_sh[t * RP + 35] = 0.0f;
    }
    for (int t = threadIdx.x; t < tot; t += 128) {
        int nl = t / FIN;
        int i = t - nl * FIN;
        long long node = node0 + nl;
        float hv = (i < 32) ? (float)h1A[(node << 5) + i]
                            : (float)h1B[(node << 2) + (i - 32)];
        h_sh[nl * RP + i] = hv;
        s_sh[nl * RP + i] = s2p[((long long)(i >> 4) * N + node) * PW2 + (i & 15)];
    }
    if (threadIdx.x < nn) b_sh[threadIdx.x] = batch[node0 + threadIdx.x];
    __syncthreads();

    int j = threadIdx.x;
    float wl[36], wr[36];
    #pragma unroll
    for (int i = 0; i < FIN; ++i) {
        wl[i] = Wl[i * FOUT + j];
        wr[i] = Wr[i * FOUT + j];
    }
    wl[35] = 0.0f; wr[35] = 0.0f;
    float blj = bl[j];

    int curg = b_sh[0];
    float m = -INFINITY;
    for (int nl = 0; nl < nn; ++nl) {
        float acc = blj;
        #pragma unroll
        for (int c = 0; c < 9; ++c) {
            float4 sv = *(const float4*)&s_sh[nl * RP + 4 * c];
            float4 hv = *(const float4*)&h_sh[nl * RP + 4 * c];
            acc = fmaf(sv.x, wl[4 * c],     acc);
            acc = fmaf(sv.y, wl[4 * c + 1], acc);
            acc = fmaf(sv.z, wl[4 * c + 2], acc);
            acc = fmaf(sv.w, wl[4 * c + 3], acc);
            acc = fmaf(hv.x, wr[4 * c],     acc);
            acc = fmaf(hv.y, wr[4 * c + 1], acc);
            acc = fmaf(hv.z, wr[4 * c + 2], acc);
            acc = fmaf(hv.w, wr[4 * c + 3], acc);
        }
        int g = b_sh[nl];   // wave-uniform
        if (g != curg) {
            atomicMax(&genc[curg * FOUT + j], enc_f32(m));
            curg = g;
            m = acc;
        } else {
            m = fmaxf(m, acc);
        }
    }
    atomicMax(&genc[curg * FOUT + j], enc_f32(m));
}

// ---------- head: one block (128 threads) per graph ----------
__global__ void head_kernel(const unsigned int* __restrict__ genc,
                            const float* __restrict__ Wg1, const float* __restrict__ bg1,
                            const float* __restrict__ Wg2, const float* __restrict__ bg2,
                            const float* __restrict__ Wo,  const float* __restrict__ bo,
                            float* __restrict__ out) {
    __shared__ float a[FOUT];
    __shared__ float c[FOUT];
    __shared__ float red[2];
    int g = blockIdx.x;
    int j = threadIdx.x;

    a[j] = dec_f32(genc[g * FOUT + j]);
    __syncthreads();

    float acc = bg1[j];
    #pragma unroll 8
    for (int i = 0; i < FOUT; ++i) acc = fmaf(a[i], Wg1[i * FOUT + j], acc);
    c[j] = fmaxf(acc, 0.0f);
    __syncthreads();

    acc = bg2[j];
    #pragma unroll 8
    for (int i = 0; i < FOUT; ++i) acc = fmaf(c[i], Wg2[i * FOUT + j], acc);
    float t = fmaxf(acc, 0.0f) * Wo[j];

    #pragma unroll
    for (int off = 32; off > 0; off >>= 1) t += __shfl_down(t, off, 64);
    if ((threadIdx.x & 63) == 0) red[threadIdx.x >> 6] = t;
    __syncthreads();
    if (threadIdx.x == 0) out[g] = red[0] + red[1] + bo[0];
}

// ---------- launch ----------
extern "C" void kernel_launch(void* const* d_in, const int* in_sizes, int n_in,
                              void* d_out, int out_size, void* d_ws, size_t ws_size,
                              hipStream_t stream) {
    const float* x    = (const float*)d_in[0];
    const int*   ei   = (const int*)  d_in[1];
    const int*   batch= (const int*)  d_in[2];
    const float* Wl1  = (const float*)d_in[3];
    const float* bl1  = (const float*)d_in[4];
    const float* Wr1  = (const float*)d_in[5];
    const float* Wl2  = (const float*)d_in[6];
    const float* bl2  = (const float*)d_in[7];
    const float* Wr2  = (const float*)d_in[8];
    const float* Wg1  = (const float*)d_in[9];
    const float* bg1  = (const float*)d_in[10];
    const float* Wg2  = (const float*)d_in[11];
    const float* bg2  = (const float*)d_in[12];
    const float* Wo   = (const float*)d_in[13];
    const float* bo   = (const float*)d_in[14];
    float* out = (float*)d_out;

    const int N = in_sizes[0] / FIN;
    const int E = in_sizes[1] / 2;
    const int* src = ei;
    const int* dst = ei + E;

    const int nblk1 = (E + CHUNK - 1) / CHUNK;          // 391
    const int nbuck = (N + 255) >> 8;                   // 391 (<= MAXBUCK)
    const int SC = nbuck * nblk1;                       // 152881
    const int NB2 = (SC + 255) / 256;                   // 598 (<= 1024)

    const size_t sp_elems = (size_t)3 * N * PW2;        // 4.8M f32 = 19.2 MB

    // workspace layout (lifetimes: ebuf -> h1A/h1B ; xA/xB -> s2p)
    char* ws = (char*)d_ws;
    size_t off = 0;
    auto alloc = [&](size_t bytes) { char* p = ws + off; off += (bytes + 255) & ~255ull; return p; };
    int*          counts  = (int*)alloc((size_t)SC * 4);
    int*          offs    = (int*)alloc((size_t)(SC + 1) * 4);
    int*          partial = (int*)alloc(1024 * 4);
    int*          row_ptr = (int*)alloc((size_t)(N + 1) * 4);
    int*          esrc    = (int*)alloc((size_t)E * 4);
    char*         regionA = (char*)alloc((size_t)E * 4);     // ebuf (12.8 MB) then h1A+h1B (7.2 MB)
    char*         regionB = (char*)alloc(sp_elems * 4);      // xA+xB (7.2 MB) then s2p f32 (19.2 MB)
    float*        s1p     = (float*)alloc(sp_elems * 4);     // 19.2 MB
    unsigned int* genc    = (unsigned int*)alloc((size_t)NGRAPHS * FOUT * 4);
    int*       ebuf = (int*)regionA;
    _Float16*  h1A  = (_Float16*)regionA;
    _Float16*  h1B  = (_Float16*)(regionA + (size_t)N * PWA * 2);
    _Float16*  xA   = (_Float16*)regionB;
    _Float16*  xB   = (_Float16*)(regionB + (size_t)N * PWA * 2);
    float*     s2p  = (float*)regionB;
    (void)ws_size; (void)n_in; (void)out_size;

    const int BS = 256;
    const int Wtot = N * 16;                             // 8N pass-A + 8N pass-B items
    int WS = ((Wtot / 8 + BS - 1) / BS) * BS;            // per-XCD share, 256-aligned
    const int bpx = WS / BS;                             // blocks per XCD share
    const int rpb = (N * 36 + BS - 1) / BS;              // repack items = N*(32+4)
    int nu1b = (N + STRIP1 - 1) / STRIP1;
    int nu2b = (N + STRIP2 - 1) / STRIP2;

    // ---- CSR build (LDS radix, no global atomics; reused by both conv layers) ----
    hipLaunchKernelGGL(hist1_kernel, dim3(nblk1), dim3(BS), 0, stream, dst, counts, E, nblk1, nbuck);
    hipLaunchKernelGGL(partial_reduce_kernel, dim3(NB2), dim3(BS), 0, stream, counts, partial, SC);
    hipLaunchKernelGGL(scan_partials_kernel, dim3(1), dim3(1024), 0, stream, partial, NB2);
    hipLaunchKernelGGL(scan_final_kernel, dim3(NB2), dim3(BS), 0, stream, counts, partial, offs, SC);
    hipLaunchKernelGGL(scatter1_kernel, dim3(nblk1), dim3(BS), 0, stream, src, dst, offs, ebuf, E, nblk1, nbuck);
    hipLaunchKernelGGL(csr2_kernel, dim3(nbuck), dim3(BS), 0, stream, ebuf, offs, row_ptr, esrc, E, nblk1, nbuck, N);

    // ---- conv1: fp16 repack -> two-pass gather -> register-weight node update ----
    hipLaunchKernelGGL(repack_kernel, dim3(rpb), dim3(BS), 0, stream, x, xA, xB, N);
    hipLaunchKernelGGL(gather2_kernel, dim3(8 * bpx), dim3(BS), 0, stream,
                       xA, xB, row_ptr, esrc, s1p, N, Wtot, WS);
    hipLaunchKernelGGL(nu1_kernel, dim3(nu1b), dim3(BS), 0, stream,
                       x, s1p, Wl1, bl1, Wr1, h1A, h1B, N);

    // ---- conv2: two-pass gather over h1 -> node update + pool ----
    hipLaunchKernelGGL(gather2_kernel, dim3(8 * bpx), dim3(BS), 0, stream,
                       h1A, h1B, row_ptr, esrc, s2p, N, Wtot, WS);
    hipMemsetAsync(genc, 0, (size_t)NGRAPHS * FOUT * 4, stream);
    hipLaunchKernelGGL(nu2_pool_kernel, dim3(nu2b), dim3(128), 0, stream,
                       h1A, h1B, s2p, Wl2, bl2, Wr2, batch, genc, N);

    // ---- head ----
    hipLaunchKernelGGL(head_kernel, dim3(NGRAPHS), dim3(FOUT), 0, stream,
                       genc, Wg1, bg1, Wg2, bg2, Wo, bo, out);
}

// Round 16
// 374.673 us; speedup vs baseline: 1.0366x; 1.0366x over previous
//
#include <hip/hip_runtime.h>
#include <hip/hip_bf16.h>
#include <math.h>

#define FIN 35
#define FOUT 128
#define NGRAPHS 512
#define PWA 32          // pass-A panel width (fp16) = 64 B rows, feats 0..31
#define PWB 4           // pass-B panel width (fp16) = 8 B rows, feats 32..34 + pad
#define RP 36           // padded LDS row (floats), 144 B: float4-aligned
#define STRIP1 64       // nodes per block in nu1 (4 waves x 16 nodes)
#define STRIP2 32       // nodes per block in nu2
#define CHUNK 8192      // edges per block in hist1/scatter1
#define MAXBUCK 512     // >= ceil(N/256)
#define MAXBE 12288     // csr2 LDS edge-staging capacity (48 KB)

typedef _Float16 half8 __attribute__((ext_vector_type(8)));
typedef _Float16 half4 __attribute__((ext_vector_type(4)));

// ---------- helpers ----------
__device__ __forceinline__ unsigned int enc_f32(float f) {
    unsigned int u = __float_as_uint(f);
    return (u & 0x80000000u) ? ~u : (u | 0x80000000u);
}
__device__ __forceinline__ float dec_f32(unsigned int u) {
    unsigned int b = (u & 0x80000000u) ? (u ^ 0x80000000u) : ~u;
    return __uint_as_float(b);
}

// ---------- CSR build via two-level LDS radix partition (no global atomics) ----------

__global__ __launch_bounds__(256) void hist1_kernel(const int* __restrict__ dst,
                                                    int* __restrict__ counts,
                                                    int E, int nblk1, int nbuck) {
    __shared__ int h[MAXBUCK];
    for (int t = threadIdx.x; t < nbuck; t += 256) h[t] = 0;
    __syncthreads();
    int base = blockIdx.x * CHUNK;
    int end = min(base + CHUNK, E);
    for (int e = base + threadIdx.x; e < end; e += 256)
        atomicAdd(&h[dst[e] >> 8], 1);
    __syncthreads();
    for (int t = threadIdx.x; t < nbuck; t += 256)
        counts[t * nblk1 + blockIdx.x] = h[t];
}

__global__ void partial_reduce_kernel(const int* __restrict__ v_in, int* __restrict__ partial, int SC) {
    int i = blockIdx.x * 256 + threadIdx.x;
    int v = (i < SC) ? v_in[i] : 0;
    #pragma unroll
    for (int off = 32; off > 0; off >>= 1) v += __shfl_down(v, off, 64);
    __shared__ int w[4];
    if ((threadIdx.x & 63) == 0) w[threadIdx.x >> 6] = v;
    __syncthreads();
    if (threadIdx.x == 0) partial[blockIdx.x] = w[0] + w[1] + w[2] + w[3];
}

__global__ void scan_partials_kernel(int* __restrict__ partial, int NB) {
    __shared__ int lds[1024];
    int t = threadIdx.x;
    int v = (t < NB) ? partial[t] : 0;
    lds[t] = v;
    __syncthreads();
    for (int off = 1; off < 1024; off <<= 1) {
        int tv = (t >= off) ? lds[t - off] : 0;
        __syncthreads();
        lds[t] += tv;
        __syncthreads();
    }
    if (t < NB) partial[t] = lds[t] - v;   // exclusive
}

__global__ void scan_final_kernel(const int* __restrict__ v_in, const int* __restrict__ partial,
                                  int* __restrict__ outx, int SC) {
    __shared__ int lds[256];
    int i = blockIdx.x * 256 + threadIdx.x;
    int v = (i < SC) ? v_in[i] : 0;
    lds[threadIdx.x] = v;
    __syncthreads();
    for (int off = 1; off < 256; off <<= 1) {
        int tv = (threadIdx.x >= off) ? lds[threadIdx.x - off] : 0;
        __syncthreads();
        lds[threadIdx.x] += tv;
        __syncthreads();
    }
    int excl = lds[threadIdx.x] - v + partial[blockIdx.x];
    if (i < SC) {
        outx[i] = excl;
        if (i == SC - 1) outx[SC] = excl + v;
    }
}

__global__ __launch_bounds__(256) void scatter1_kernel(const int* __restrict__ src,
                                                       const int* __restrict__ dst,
                                                       const int* __restrict__ offs,
                                                       int* __restrict__ ebuf,
                                                       int E, int nblk1, int nbuck) {
    __shared__ int cur[MAXBUCK];
    for (int t = threadIdx.x; t < nbuck; t += 256) cur[t] = offs[t * nblk1 + blockIdx.x];
    __syncthreads();
    int base = blockIdx.x * CHUNK;
    int end = min(base + CHUNK, E);
    for (int e = base + threadIdx.x; e < end; e += 256) {
        int d = dst[e];
        int p = atomicAdd(&cur[d >> 8], 1);
        ebuf[p] = (src[e] << 8) | (d & 255);
    }
}

// Level-2: one block per bucket; bucket edges staged in LDS. Builds row_ptr AND the
// src-half split point hsplit[n] (512 bins: node_local x (src>=N/2)) so each node's
// list is [low-src half | high-src half] -> gather pass A1/A2 touch 3.2 MB each.
__global__ __launch_bounds__(256) void csr2_kernel(const int* __restrict__ ebuf,
                                                   const int* __restrict__ offs,
                                                   int* __restrict__ row_ptr,
                                                   int* __restrict__ hsplit,
                                                   int* __restrict__ esrc,
                                                   int E, int nblk1, int nbuck, int N, int halfN) {
    __shared__ int h[512];
    __shared__ int scn[256];
    __shared__ int cur[512];
    __shared__ int e_sh[MAXBE];
    int b = blockIdx.x;
    int t = threadIdx.x;
    int bstart = offs[b * nblk1];
    int bend = (b + 1 < nbuck) ? offs[(b + 1) * nblk1] : E;
    int cnt = bend - bstart;
    bool fit = (cnt <= MAXBE);

    if (fit)
        for (int k = t; k < cnt; k += 256) e_sh[k] = ebuf[bstart + k];
    h[t] = 0; h[t + 256] = 0;
    __syncthreads();
    for (int k = t; k < cnt; k += 256) {
        int e = fit ? e_sh[k] : ebuf[bstart + k];
        int bin = ((e & 255) << 1) | ((e >> 8) >= halfN ? 1 : 0);
        atomicAdd(&h[bin], 1);
    }
    __syncthreads();

    int v0 = h[2 * t];
    int v1 = h[2 * t + 1];
    int pair = v0 + v1;
    scn[t] = pair;
    __syncthreads();
    for (int off = 1; off < 256; off <<= 1) {
        int tv = (t >= off) ? scn[t - off] : 0;
        __syncthreads();
        scn[t] += tv;
        __syncthreads();
    }
    int base = bstart + scn[t] - pair;       // exclusive pair prefix
    int node = (b << 8) + t;
    if (node < N) {
        row_ptr[node] = base;
        hsplit[node] = base + v0;
    }
    if (b == 0 && t == 0) row_ptr[N] = E;
    cur[2 * t] = base;
    cur[2 * t + 1] = base + v0;
    __syncthreads();

    for (int k = t; k < cnt; k += 256) {
        int e = fit ? e_sh[k] : ebuf[bstart + k];
        int bin = ((e & 255) << 1) | ((e >> 8) >= halfN ? 1 : 0);
        int p = atomicAdd(&cur[bin], 1);
        esrc[p] = e >> 8;
    }
}

// ---------- repack x[N][35] -> xA[N][32] (64 B rows) + xB[N][4] (8 B rows, pad zero) ----------
__global__ void repack_kernel(const float* __restrict__ x,
                              _Float16* __restrict__ xA, _Float16* __restrict__ xB, int N) {
    int t = blockIdx.x * 256 + threadIdx.x;          // < N*36
    int NA = N * PWA;
    if (t < NA) {
        int n = t >> 5;
        int f = t & 31;
        xA[t] = (_Float16)x[(long long)n * FIN + f];
    } else if (t < NA + N * PWB) {
        int c = t - NA;
        int n = c >> 2;
        int f3 = c & 3;
        float v = (f3 < 3) ? x[(long long)n * FIN + 32 + f3] : 0.0f;
        xB[c] = (_Float16)v;
    }
}

// ---------- three-pass XCD-affinity gather, 2 random line transactions per edge ----------
// Pass A1: feats 0-31 over low-src sub-list (xA rows < N/2, 3.2 MB); pass A2: high-src
// sub-list (other 3.2 MB); pass B: feats 32-34 over full list (0.8 MB panel). Every
// panel is L2-resident (round 15's 6.4 MB panel was not); each edge is read by exactly
// one A pass (one 64 B line via 4-quad-lane coalescing, verified round 15) + pass B.
// A passes write raw sums to disjoint buffers (XCD order undefined -> no RMW); nu adds
// halves and folds 1/deg into its epilogue. Item = 8/node/pass, Wtot = 24N.
__global__ __launch_bounds__(256) void gather3_kernel(const _Float16* __restrict__ pA,
                                                      const _Float16* __restrict__ pB,
                                                      const int* __restrict__ row_ptr,
                                                      const int* __restrict__ hsplit,
                                                      const int* __restrict__ esrc,
                                                      float* __restrict__ spA,
                                                      float* __restrict__ spB,
                                                      int N, int Wtot, int WS) {
    int q = blockIdx.x & 7;
    int m = blockIdx.x >> 3;
    int w = q * WS + m * 256 + threadIdx.x;
    int wend = min((q + 1) * WS, Wtot);
    if (w >= wend) return;
    int NI = N * 8;
    int pass = w / NI;                       // 0 = A1 (low src), 1 = A2 (high src), 2 = B
    int t = w - pass * NI;
    int n = t >> 3;

    if (pass < 2) {
        int quad = (t >> 1) & 3;             // feature octet within the 64 B row
        int q2 = t & 1;                      // sub-list half
        int b = (pass == 0) ? row_ptr[n] : hsplit[n];
        int e = (pass == 0) ? hsplit[n] : row_ptr[n + 1];
        int len = e - b;
        int k0 = b + ((len * q2) >> 1);
        int k1 = b + ((len * (q2 + 1)) >> 1);
        const _Float16* base = pA + (quad << 3);

        float a0[8] = {0,0,0,0,0,0,0,0}, a1[8] = {0,0,0,0,0,0,0,0};
        float a2[8] = {0,0,0,0,0,0,0,0}, a3[8] = {0,0,0,0,0,0,0,0};
        int k = k0;
        for (; k + 4 <= k1; k += 4) {
            int s0 = esrc[k], s1 = esrc[k + 1], s2 = esrc[k + 2], s3 = esrc[k + 3];
            half8 v0 = *(const half8*)(base + ((long long)s0 << 5));
            half8 v1 = *(const half8*)(base + ((long long)s1 << 5));
            half8 v2 = *(const half8*)(base + ((long long)s2 << 5));
            half8 v3 = *(const half8*)(base + ((long long)s3 << 5));
            #pragma unroll
            for (int i = 0; i < 8; ++i) {
                a0[i] += (float)v0[i];
                a1[i] += (float)v1[i];
                a2[i] += (float)v2[i];
                a3[i] += (float)v3[i];
            }
        }
        for (; k < k1; ++k) {
            half8 v = *(const half8*)(base + ((long long)esrc[k] << 5));
            #pragma unroll
            for (int i = 0; i < 8; ++i) a0[i] += (float)v[i];
        }

        float s[8];
        #pragma unroll
        for (int i = 0; i < 8; ++i) {
            float p = (a0[i] + a1[i]) + (a2[i] + a3[i]);
            p += __shfl_xor(p, 1, 64);       // combine the two q2 halves
            s[i] = p;
        }
        if (q2 == 0) {                       // raw sums, no division
            float* outp = spA + ((long long)pass * N + n) * PWA + (quad << 3);
            float4 r0, r1;
            r0.x = s[0]; r0.y = s[1]; r0.z = s[2]; r0.w = s[3];
            r1.x = s[4]; r1.y = s[5]; r1.z = s[6]; r1.w = s[7];
            *(float4*)outp = r0;
            *(float4*)(outp + 4) = r1;
        }
    } else {
        int q8 = t & 7;                      // edge-list eighth
        int b = row_ptr[n];
        int e = row_ptr[n + 1];
        int len = e - b;
        int k0 = b + ((len * q8) >> 3);
        int k1 = b + ((len * (q8 + 1)) >> 3);

        float a0[4] = {0,0,0,0}, a1[4] = {0,0,0,0};
        int k = k0;
        for (; k + 2 <= k1; k += 2) {
            int s0 = esrc[k], s1 = esrc[k + 1];
            half4 v0 = *(const half4*)(pB + ((long long)s0 << 2));
            half4 v1 = *(const half4*)(pB + ((long long)s1 << 2));
            #pragma unroll
            for (int i = 0; i < 4; ++i) {
                a0[i] += (float)v0[i];
                a1[i] += (float)v1[i];
            }
        }
        for (; k < k1; ++k) {
            half4 v = *(const half4*)(pB + ((long long)esrc[k] << 2));
            #pragma unroll
            for (int i = 0; i < 4; ++i) a0[i] += (float)v[i];
        }

        float s[4];
        #pragma unroll
        for (int i = 0; i < 4; ++i) {
            float p = a0[i] + a1[i];
            p += __shfl_xor(p, 1, 64);
            p += __shfl_xor(p, 2, 64);
            p += __shfl_xor(p, 4, 64);
            s[i] = p;
        }
        if (q8 == 0) {                       // raw sums
            float4 r;
            r.x = s[0]; r.y = s[1]; r.z = s[2]; r.w = s[3];
            *(float4*)(spB + ((long long)n << 2)) = r;
        }
    }
}

// ---------- nu1: h1 = relu((sum/deg)@Wl1 + bl1 + x@Wr1) ----------
// Weights in registers; float4 broadcast reads from padded LDS rows; raw sums staged
// (A1+A2 halves added), 1/deg folded into the epilogue via separate accS/accX.
__global__ __launch_bounds__(256) void nu1_kernel(const float* __restrict__ x,
                                                  const float* __restrict__ spA,
                                                  const float* __restrict__ spB,
                                                  const int* __restrict__ row_ptr,
                                                  const float* __restrict__ Wl,
                                                  const float* __restrict__ bl,
                                                  const float* __restrict__ Wr,
                                                  _Float16* __restrict__ h1A,
                                                  _Float16* __restrict__ h1B,
                                                  int N) {
    __shared__ float x_sh[STRIP1 * RP];
    __shared__ float s_sh[STRIP1 * RP];
    __shared__ int deg_sh[STRIP1];

    int node0 = blockIdx.x * STRIP1;
    if (node0 >= N) return;
    int nn = min(STRIP1, N - node0);
    int tot = nn * FIN;

    for (int t = threadIdx.x; t < STRIP1; t += 256) {
        x_sh[t * RP + 35] = 0.0f;
        s_sh[t * RP + 35] = 0.0f;
    }
    if (threadIdx.x < nn)
        deg_sh[threadIdx.x] = row_ptr[node0 + threadIdx.x + 1] - row_ptr[node0 + threadIdx.x];
    for (int t = threadIdx.x; t < tot; t += 256) {
        int nl = t / FIN;
        int i = t - nl * FIN;
        long long node = node0 + nl;
        x_sh[nl * RP + i] = x[node * FIN + i];
        float sv = (i < 32) ? (spA[node * PWA + i] + spA[((long long)N + node) * PWA + i])
                            : spB[(node << 2) + (i - 32)];
        s_sh[nl * RP + i] = sv;
    }
    __syncthreads();

    int wave = threadIdx.x >> 6;
    int j = threadIdx.x & 63;
    if (j >= FIN) return;                    // no further barriers below

    float wl[36], wr[36];
    #pragma unroll
    for (int i = 0; i < FIN; ++i) {
        wl[i] = Wl[i * FIN + j];
        wr[i] = Wr[i * FIN + j];
    }
    wl[35] = 0.0f; wr[35] = 0.0f;
    float blj = bl[j];

    int nstart = wave * 16;
    int nend = min(nstart + 16, nn);
    for (int nl = nstart; nl < nend; ++nl) {
        float accS = 0.0f;
        float accX = blj;
        #pragma unroll
        for (int c = 0; c < 9; ++c) {
            float4 sv = *(const float4*)&s_sh[nl * RP + 4 * c];
            float4 xv = *(const float4*)&x_sh[nl * RP + 4 * c];
            accS = fmaf(sv.x, wl[4 * c],     accS);
            accS = fmaf(sv.y, wl[4 * c + 1], accS);
            accS = fmaf(sv.z, wl[4 * c + 2], accS);
            accS = fmaf(sv.w, wl[4 * c + 3], accS);
            accX = fmaf(xv.x, wr[4 * c],     accX);
            accX = fmaf(xv.y, wr[4 * c + 1], accX);
            accX = fmaf(xv.z, wr[4 * c + 2], accX);
            accX = fmaf(xv.w, wr[4 * c + 3], accX);
        }
        float inv = 1.0f / (float)max(deg_sh[nl], 1);
        float acc = fmaxf(fmaf(accS, inv, accX), 0.0f);
        long long node = node0 + nl;
        if (j < 32) {
            h1A[(node << 5) + j] = (_Float16)acc;
        } else {
            h1B[(node << 2) + (j - 32)] = (_Float16)acc;
            if (j == 34) h1B[(node << 2) + 3] = (_Float16)0.0f;   // keep pad clean
        }
    }
}

// ---------- nu2 + pool: h2 = (sum/deg)@Wl2 + bl2 + h1@Wr2, segment-batched graph max ----------
__global__ __launch_bounds__(128) void nu2_pool_kernel(const _Float16* __restrict__ h1A,
                                                       const _Float16* __restrict__ h1B,
                                                       const float* __restrict__ spA,
                                                       const float* __restrict__ spB,
                                                       const int* __restrict__ row_ptr,
                                                       const float* __restrict__ Wl,
                                                       const float* __restrict__ bl,
                                                       const float* __restrict__ Wr,
                                                       const int* __restrict__ batch,
                                                       unsigned int* __restrict__ genc,
                                                       int N) {
    __shared__ float s_sh[STRIP2 * RP];
    __shared__ float h_sh[STRIP2 * RP];
    __shared__ int b_sh[STRIP2];
    __shared__ int deg_sh[STRIP2];
    int node0 = blockIdx.x * STRIP2;
    if (node0 >= N) return;
    int nn = min(STRIP2, N - node0);
    int tot = nn * FIN;

    for (int t = threadIdx.x; t < STRIP2; t += 128) {
        s_sh[t * RP + 35] = 0.0f;
        h_sh[t * RP + 35] = 0.0f;
    }
    if (threadIdx.x < nn) {
        b_sh[threadIdx.x] = batch[node0 + threadIdx.x];
        deg_sh[threadIdx.x] = row_ptr[node0 + threadIdx.x + 1] - row_ptr[node0 + threadIdx.x];
    }
    for (int t = threadIdx.x; t < tot; t += 128) {
        int nl = t / FIN;
        int i = t - nl * FIN;
        long long node = node0 + nl;
        float hv = (i < 32) ? (float)h1A[(node << 5) + i]
                            : (float)h1B[(node << 2) + (i - 32)];
        h_sh[nl * RP + i] = hv;
        float sv = (i < 32) ? (spA[node * PWA + i] + spA[((long long)N + node) * PWA + i])
                            : spB[(node << 2) + (i - 32)];
        s_sh[nl * RP + i] = sv;
    }
    __syncthreads();

    int j = threadIdx.x;
    float wl[36], wr[36];
    #pragma unroll
    for (int i = 0; i < FIN; ++i) {
        wl[i] = Wl[i * FOUT + j];
        wr[i] = Wr[i * FOUT + j];
    }
    wl[35] = 0.0f; wr[35] = 0.0f;
    float blj = bl[j];

    int curg = b_sh[0];
    float m = -INFINITY;
    for (int nl = 0; nl < nn; ++nl) {
        float accS = 0.0f;
        float accH = blj;
        #pragma unroll
        for (int c = 0; c < 9; ++c) {
            float4 sv = *(const float4*)&s_sh[nl * RP + 4 * c];
            float4 hv = *(const float4*)&h_sh[nl * RP + 4 * c];
            accS = fmaf(sv.x, wl[4 * c],     accS);
            accS = fmaf(sv.y, wl[4 * c + 1], accS);
            accS = fmaf(sv.z, wl[4 * c + 2], accS);
            accS = fmaf(sv.w, wl[4 * c + 3], accS);
            accH = fmaf(hv.x, wr[4 * c],     accH);
            accH = fmaf(hv.y, wr[4 * c + 1], accH);
            accH = fmaf(hv.z, wr[4 * c + 2], accH);
            accH = fmaf(hv.w, wr[4 * c + 3], accH);
        }
        float inv = 1.0f / (float)max(deg_sh[nl], 1);
        float acc = fmaf(accS, inv, accH);
        int g = b_sh[nl];   // wave-uniform
        if (g != curg) {
            atomicMax(&genc[curg * FOUT + j], enc_f32(m));
            curg = g;
            m = acc;
        } else {
            m = fmaxf(m, acc);
        }
    }
    atomicMax(&genc[curg * FOUT + j], enc_f32(m));
}

// ---------- head: one block (128 threads) per graph ----------
__global__ void head_kernel(const unsigned int* __restrict__ genc,
                            const float* __restrict__ Wg1, const float* __restrict__ bg1,
                            const float* __restrict__ Wg2, const float* __restrict__ bg2,
                            const float* __restrict__ Wo,  const float* __restrict__ bo,
                            float* __restrict__ out) {
    __shared__ float a[FOUT];
    __shared__ float c[FOUT];
    __shared__ float red[2];
    int g = blockIdx.x;
    int j = threadIdx.x;

    a[j] = dec_f32(genc[g * FOUT + j]);
    __syncthreads();

    float acc = bg1[j];
    #pragma unroll 8
    for (int i = 0; i < FOUT; ++i) acc = fmaf(a[i], Wg1[i * FOUT + j], acc);
    c[j] = fmaxf(acc, 0.0f);
    __syncthreads();

    acc = bg2[j];
    #pragma unroll 8
    for (int i = 0; i < FOUT; ++i) acc = fmaf(c[i], Wg2[i * FOUT + j], acc);
    float t = fmaxf(acc, 0.0f) * Wo[j];

    #pragma unroll
    for (int off = 32; off > 0; off >>= 1) t += __shfl_down(t, off, 64);
    if ((threadIdx.x & 63) == 0) red[threadIdx.x >> 6] = t;
    __syncthreads();
    if (threadIdx.x == 0) out[g] = red[0] + red[1] + bo[0];
}

// ---------- launch ----------
extern "C" void kernel_launch(void* const* d_in, const int* in_sizes, int n_in,
                              void* d_out, int out_size, void* d_ws, size_t ws_size,
                              hipStream_t stream) {
    const float* x    = (const float*)d_in[0];
    const int*   ei   = (const int*)  d_in[1];
    const int*   batch= (const int*)  d_in[2];
    const float* Wl1  = (const float*)d_in[3];
    const float* bl1  = (const float*)d_in[4];
    const float* Wr1  = (const float*)d_in[5];
    const float* Wl2  = (const float*)d_in[6];
    const float* bl2  = (const float*)d_in[7];
    const float* Wr2  = (const float*)d_in[8];
    const float* Wg1  = (const float*)d_in[9];
    const float* bg1  = (const float*)d_in[10];
    const float* Wg2  = (const float*)d_in[11];
    const float* bg2  = (const float*)d_in[12];
    const float* Wo   = (const float*)d_in[13];
    const float* bo   = (const float*)d_in[14];
    float* out = (float*)d_out;

    const int N = in_sizes[0] / FIN;
    const int E = in_sizes[1] / 2;
    const int* src = ei;
    const int* dst = ei + E;
    const int halfN = N >> 1;

    const int nblk1 = (E + CHUNK - 1) / CHUNK;          // 391
    const int nbuck = (N + 255) >> 8;                   // 391 (<= MAXBUCK)
    const int SC = nbuck * nblk1;                       // 152881
    const int NB2 = (SC + 255) / 256;                   // 598 (<= 1024)

    // workspace layout (lifetimes: ebuf -> h1A/h1B)
    char* ws = (char*)d_ws;
    size_t off = 0;
    auto alloc = [&](size_t bytes) { char* p = ws + off; off += (bytes + 255) & ~255ull; return p; };
    int*          counts  = (int*)alloc((size_t)SC * 4);
    int*          offs    = (int*)alloc((size_t)(SC + 1) * 4);
    int*          partial = (int*)alloc(1024 * 4);
    int*          row_ptr = (int*)alloc((size_t)(N + 1) * 4);
    int*          hsplit  = (int*)alloc((size_t)N * 4);
    int*          esrc    = (int*)alloc((size_t)E * 4);
    char*         regionA = (char*)alloc((size_t)E * 4);          // ebuf (12.8 MB) then h1A+h1B (7.2 MB)
    _Float16*     xA      = (_Float16*)alloc((size_t)N * PWA * 2);
    _Float16*     xB      = (_Float16*)alloc((size_t)N * PWB * 2);
    float*        spA     = (float*)alloc((size_t)2 * N * PWA * 4);  // raw sums, halves 0/1 (25.6 MB)
    float*        spB     = (float*)alloc((size_t)N * PWB * 4);      // raw sums feats 32-34 (1.6 MB)
    unsigned int* genc    = (unsigned int*)alloc((size_t)NGRAPHS * FOUT * 4);
    int*       ebuf = (int*)regionA;
    _Float16*  h1A  = (_Float16*)regionA;
    _Float16*  h1B  = (_Float16*)(regionA + (size_t)N * PWA * 2);
    (void)ws_size; (void)n_in; (void)out_size;

    const int BS = 256;
    const int Wtot = N * 24;                             // 8N per pass x 3 passes
    int WS = ((Wtot / 8 + BS - 1) / BS) * BS;            // per-XCD share, 256-aligned
    const int bpx = WS / BS;                             // blocks per XCD share
    const int rpb = (N * 36 + BS - 1) / BS;              // repack items = N*(32+4)
    int nu1b = (N + STRIP1 - 1) / STRIP1;
    int nu2b = (N + STRIP2 - 1) / STRIP2;

    // ---- CSR build (LDS radix, no global atomics; reused by both conv layers) ----
    hipLaunchKernelGGL(hist1_kernel, dim3(nblk1), dim3(BS), 0, stream, dst, counts, E, nblk1, nbuck);
    hipLaunchKernelGGL(partial_reduce_kernel, dim3(NB2), dim3(BS), 0, stream, counts, partial, SC);
    hipLaunchKernelGGL(scan_partials_kernel, dim3(1), dim3(1024), 0, stream, partial, NB2);
    hipLaunchKernelGGL(scan_final_kernel, dim3(NB2), dim3(BS), 0, stream, counts, partial, offs, SC);
    hipLaunchKernelGGL(scatter1_kernel, dim3(nblk1), dim3(BS), 0, stream, src, dst, offs, ebuf, E, nblk1, nbuck);
    hipLaunchKernelGGL(csr2_kernel, dim3(nbuck), dim3(BS), 0, stream,
                       ebuf, offs, row_ptr, hsplit, esrc, E, nblk1, nbuck, N, halfN);

    // ---- conv1: fp16 repack -> three-pass gather (2 lines/edge) -> node update ----
    hipLaunchKernelGGL(repack_kernel, dim3(rpb), dim3(BS), 0, stream, x, xA, xB, N);
    hipLaunchKernelGGL(gather3_kernel, dim3(8 * bpx), dim3(BS), 0, stream,
                       xA, xB, row_ptr, hsplit, esrc, spA, spB, N, Wtot, WS);
    hipLaunchKernelGGL(nu1_kernel, dim3(nu1b), dim3(BS), 0, stream,
                       x, spA, spB, row_ptr, Wl1, bl1, Wr1, h1A, h1B, N);

    // ---- conv2: three-pass gather over h1 -> node update + pool (sp buffers reused) ----
    hipLaunchKernelGGL(gather3_kernel, dim3(8 * bpx), dim3(BS), 0, stream,
                       h1A, h1B, row_ptr, hsplit, esrc, spA, spB, N, Wtot, WS);
    hipMemsetAsync(genc, 0, (size_t)NGRAPHS * FOUT * 4, stream);
    hipLaunchKernelGGL(nu2_pool_kernel, dim3(nu2b), dim3(128), 0, stream,
                       h1A, h1B, spA, spB, row_ptr, Wl2, bl2, Wr2, batch, genc, N);

    // ---- head ----
    hipLaunchKernelGGL(head_kernel, dim3(NGRAPHS), dim3(FOUT), 0, stream,
                       genc, Wg1, bg1, Wg2, bg2, Wo, bo, out);
}